// Round 3
// 1275.362 us; speedup vs baseline: 1.1724x; 1.1724x over previous
//
#include <hip/hip_runtime.h>

#define HW 65536
#define STRIDE 68   // padded LDS row stride in floats (16B-aligned, breaks bank degeneracy)

typedef float          f32x4  __attribute__((ext_vector_type(4)));
typedef __bf16         bf16x8 __attribute__((ext_vector_type(8)));
typedef unsigned short u16x8  __attribute__((ext_vector_type(8)));

// ws (__bf16 element offsets): 15 weight mats, m = type*3 + L (type: 0 enc, 1 qh, 2 dq, 3 rh, 4 lh)
// base m*12288, split levels at +0 / +4096 / +8192, layout [col][k] (transposed for B-frags)

__device__ __forceinline__ f32x4 mfma16(bf16x8 a, bf16x8 b, f32x4 c) {
    return __builtin_amdgcn_mfma_f32_16x16x32_bf16(a, b, c, 0, 0, 0);
}

// -------- 3-level bf16 split via BIT OPS ONLY (no fp<->bf16 conversions the
// compiler can fold): l1+l2+l3 captures the full 24-bit fp32 mantissa (8+8+8),
// residual <= 2^-24 |x|. Subtractions are exact (trailing mantissa bits only).
struct AFrag { bf16x8 a1[2], a2[2], a3[2]; };   // 3 levels x 2 K-tiles

__device__ __forceinline__ void split3_8(const float* f, bf16x8* v1, bf16x8* v2, bf16x8* v3) {
    u16x8 a, b, c;
    #pragma unroll
    for (int i = 0; i < 8; ++i) {
        const float    x  = f[i];
        const unsigned u1 = __float_as_uint(x) & 0xFFFF0000u;
        const float    r1 = x - __uint_as_float(u1);          // exact
        const unsigned u2 = __float_as_uint(r1) & 0xFFFF0000u;
        const float    r2 = r1 - __uint_as_float(u2);         // exact
        const unsigned u3 = __float_as_uint(r2) & 0xFFFF0000u;
        a[i] = (unsigned short)(u1 >> 16);
        b[i] = (unsigned short)(u2 >> 16);
        c[i] = (unsigned short)(u3 >> 16);
    }
    union { u16x8 u; bf16x8 b; } cv;
    cv.u = a; *v1 = cv.b;
    cv.u = b; *v2 = cv.b;
    cv.u = c; *v3 = cv.b;
}

// A-frag for mfma_f32_16x16x32_bf16: row = lane&15, k = (lane>>4)*8 + j
__device__ __forceinline__ AFrag load_afrag(const float* __restrict__ buf, int rbase, int lane) {
    const int r  = rbase + (lane & 15);
    const int k0 = (lane >> 4) * 8;
    const float* p = buf + r * STRIDE + k0;
    float f[16];
    *(float4*)(f + 0)  = *(const float4*)(p + 0);
    *(float4*)(f + 4)  = *(const float4*)(p + 4);
    *(float4*)(f + 8)  = *(const float4*)(p + 32);
    *(float4*)(f + 12) = *(const float4*)(p + 36);
    AFrag A;
    split3_8(f,     &A.a1[0], &A.a2[0], &A.a3[0]);
    split3_8(f + 8, &A.a1[1], &A.a2[1], &A.a3[1]);
    return A;
}

// dst = src @ W + b  over a 64x64 tile; wave w owns rows [16w,16w+16), all 4 col-tiles.
// 12 MFMAs/tile = split products (1,1)(2,1)(3,1)(1,2)(2,2)(1,3) x 2 K-tiles -> ~fp32-equiv.
// MODE 0: store dst; 1: store dst + save C-frags; 2: sav[] += result (+bias); 3: store dst - sav[]
template<int MODE>
__device__ __forceinline__ void mm64(float* __restrict__ dst, const float* __restrict__ src,
                                     const __bf16* __restrict__ wt, const float* __restrict__ bias,
                                     f32x4* __restrict__ sav, int lane, int w)
{
    const AFrag A = load_afrag(src, w * 16, lane);
    const int lc = lane & 15;
    const int kg = (lane >> 4) * 8;
    const int rg = (lane >> 4) * 4;
    #pragma unroll
    for (int ct = 0; ct < 4; ++ct) {
        const int col = ct * 16 + lc;
        const __bf16* wp = wt + col * 64 + kg;          // B-frag: col = lane&15, k = (lane>>4)*8+j
        const bf16x8 b10 = *(const bf16x8*)(wp);
        const bf16x8 b11 = *(const bf16x8*)(wp + 32);
        const bf16x8 b20 = *(const bf16x8*)(wp + 4096);
        const bf16x8 b21 = *(const bf16x8*)(wp + 4096 + 32);
        const bf16x8 b30 = *(const bf16x8*)(wp + 8192);
        const bf16x8 b31 = *(const bf16x8*)(wp + 8192 + 32);
        const float bv = bias[col];
        f32x4 acc;
        if (MODE == 2) { acc = sav[ct]; acc.x += bv; acc.y += bv; acc.z += bv; acc.w += bv; }
        else           { acc.x = bv; acc.y = bv; acc.z = bv; acc.w = bv; }
        acc = mfma16(A.a1[0], b10, acc); acc = mfma16(A.a1[1], b11, acc);
        acc = mfma16(A.a2[0], b10, acc); acc = mfma16(A.a2[1], b11, acc);
        acc = mfma16(A.a3[0], b10, acc); acc = mfma16(A.a3[1], b11, acc);
        acc = mfma16(A.a1[0], b20, acc); acc = mfma16(A.a1[1], b21, acc);
        acc = mfma16(A.a2[0], b20, acc); acc = mfma16(A.a2[1], b21, acc);
        acc = mfma16(A.a1[0], b30, acc); acc = mfma16(A.a1[1], b31, acc);
        if (MODE == 2) { sav[ct] = acc; continue; }
        if (MODE == 1) sav[ct] = acc;
        if (MODE == 3) { const f32x4 d = sav[ct]; acc.x -= d.x; acc.y -= d.y; acc.z -= d.z; acc.w -= d.w; }
        // C-frag: col = lane&15, row = (lane>>4)*4 + j   [measured m89]
        #pragma unroll
        for (int j = 0; j < 4; ++j)
            dst[(w * 16 + rg + j) * STRIDE + col] = acc[j];
    }
}

// ---------------- prep: bit-split weights (transposed) into ws ----------------
__global__ __launch_bounds__(256)
void hpp_prep(const float* __restrict__ W_enc, const float* __restrict__ W_qh,
              const float* __restrict__ W_dq,  const float* __restrict__ W_rh,
              const float* __restrict__ W_lh,
              __bf16* __restrict__ ws)
{
    const int i = blockIdx.x * 256 + threadIdx.x;
    if (i < 61440) {                       // 15 mats x 4096
        const int m = i >> 12, e = i & 4095;
        const int t = m / 3, L = m - t * 3;
        const int c = e >> 6, k = e & 63;
        const float* W = (t == 0) ? W_enc : (t == 1) ? W_qh : (t == 2) ? W_dq
                                        : (t == 3) ? W_rh : W_lh;
        const float    fv = W[L * 4096 + k * 64 + c];
        const unsigned u1 = __float_as_uint(fv) & 0xFFFF0000u;
        const float    r1 = fv - __uint_as_float(u1);
        const unsigned u2 = __float_as_uint(r1) & 0xFFFF0000u;
        const float    r2 = r1 - __uint_as_float(u2);
        const unsigned u3 = __float_as_uint(r2) & 0xFFFF0000u;
        unsigned short* wp = (unsigned short*)(ws + m * 12288 + c * 64 + k);  // transposed: [col][k]
        wp[0]    = (unsigned short)(u1 >> 16);
        wp[4096] = (unsigned short)(u2 >> 16);
        wp[8192] = (unsigned short)(u3 >> 16);
    }
}

// ---------------- main fused kernel: 64 rows / block ----------------
__global__ __launch_bounds__(256, 2)
void hpp_fused(const float* __restrict__ x,
               const float* __restrict__ b_enc, const float* __restrict__ b_qh,
               const float* __restrict__ b_lh,  const float* __restrict__ b_dq,
               const float* __restrict__ b_rh,
               const float* __restrict__ cbk,   const __bf16* __restrict__ ws,
               float* __restrict__ out, float* __restrict__ loss_out)
{
    __shared__ __align__(16) float buf0[64 * STRIDE];
    __shared__ __align__(16) float buf1[64 * STRIDE];
    __shared__ __align__(16) float buf2[64 * STRIDE];
    __shared__ float cc[256];
    __shared__ float red_d[256];
    __shared__ int   red_i[256];
    __shared__ float wred[4];

    const int t   = threadIdx.x;
    const int n0  = blockIdx.x * 64;
    const int b   = n0 >> 16;
    const int hw0 = n0 & (HW - 1);
    const size_t base = (size_t)b * 64 * HW + hw0;

    float* rb = buf0;   // residual (then codebook chunk, then deq)
    float* zb = buf1;   // z (then restored staging)
    float* qb = buf2;   // q (then quant, then next residual)

    for (int i = 0; i < 16; ++i) {
        const int e = t + 256 * i;
        const int c = e >> 6, r = e & 63;
        rb[r * STRIDE + c] = x[base + (size_t)c * HW + r];
    }

    const int lane = t & 63;
    const int w    = t >> 6;         // wave id (row-block for GEMMs)
    const int lc   = lane & 15;
    const int g2   = lane >> 4;

    f32x4 restored[4] = {};
    f32x4 deqf[4];
    float loss_acc = 0.f;

    __syncthreads();

    for (int L = 0; L < 3; ++L) {
        const __bf16* wtE = ws + (0 * 3 + L) * 12288;
        const __bf16* wtQ = ws + (1 * 3 + L) * 12288;
        const __bf16* wtD = ws + (2 * 3 + L) * 12288;
        const __bf16* wtR = ws + (3 * 3 + L) * 12288;
        const __bf16* wtL = ws + (4 * 3 + L) * 12288;

        mm64<0>(zb, rb, wtE, b_enc + L * 64, nullptr, lane, w);   // z = r@We + b
        __syncthreads();
        mm64<0>(qb, zb, wtQ, b_qh + L * 64, nullptr, lane, w);    // q = z@Wq + b

        // ---- VQ scan: EXACT arithmetic of the proven fp32 kernel ----
        for (int s = 0; s < 4; ++s) {
            __syncthreads();   // q_buf visible; prior chunk readers done
            const float4* __restrict__ cbs4 = (const float4*)(cbk + (size_t)(L * 4 + s) * 4096);
            float4* __restrict__ rb4 = (float4*)rb;
            #pragma unroll
            for (int i = 0; i < 4; ++i)
                rb4[t + 256 * i] = cbs4[t + 256 * i];
            __syncthreads();
            {   // cc[m] = ||cb[m]||^2, one code per thread
                float s0 = 0, s1 = 0, s2 = 0, s3 = 0;
                const float* cp = rb + t * 16;
                #pragma unroll
                for (int d4 = 0; d4 < 4; ++d4) {
                    const float4 v = *(const float4*)(cp + 4 * d4);
                    s0 = fmaf(v.x, v.x, s0); s1 = fmaf(v.y, v.y, s1);
                    s2 = fmaf(v.z, v.z, s2); s3 = fmaf(v.w, v.w, s3);
                }
                cc[t] = (s0 + s1) + (s2 + s3);
            }
            __syncthreads();
            {   // scan: thread = (row, quarter of codes); codebook reads are wave-uniform broadcasts
                const int row = t & 63, qt = t >> 6;
                float qv[16];
                const float* qp = qb + row * STRIDE + s * 16;
                #pragma unroll
                for (int d4 = 0; d4 < 4; ++d4) {
                    const float4 v = *(const float4*)(qp + 4 * d4);
                    qv[4 * d4 + 0] = v.x; qv[4 * d4 + 1] = v.y;
                    qv[4 * d4 + 2] = v.z; qv[4 * d4 + 3] = v.w;
                }
                float qq = 0.f;
                #pragma unroll
                for (int d = 0; d < 16; ++d) qq = fmaf(qv[d], qv[d], qq);
                float best = 3.4e38f; int bi = 0;
                #pragma unroll 2
                for (int mi = 0; mi < 64; ++mi) {
                    const int m = qt * 64 + mi;
                    const float* cp = rb + m * 16;
                    float d0 = 0, d1 = 0, d2 = 0, d3 = 0;
                    #pragma unroll
                    for (int d4 = 0; d4 < 4; ++d4) {
                        const float4 v = *(const float4*)(cp + 4 * d4);
                        d0 = fmaf(qv[4 * d4 + 0], v.x, d0);
                        d1 = fmaf(qv[4 * d4 + 1], v.y, d1);
                        d2 = fmaf(qv[4 * d4 + 2], v.z, d2);
                        d3 = fmaf(qv[4 * d4 + 3], v.w, d3);
                    }
                    const float dot  = (d0 + d1) + (d2 + d3);
                    const float dist = qq - 2.0f * dot + cc[m];   // same formula as reference
                    if (dist < best) { best = dist; bi = m; }     // strict <  => first-min (jnp argmin)
                }
                red_d[qt * 64 + row] = best;
                red_i[qt * 64 + row] = bi;
            }
            __syncthreads();
            if (t < 64) {   // combine quarters (ascending => lowest index on exact tie), quantize + loss
                const int row = t;
                float best = red_d[row]; int bi = red_i[row];
                #pragma unroll
                for (int qt = 1; qt < 4; ++qt) {
                    const float dv = red_d[qt * 64 + row];
                    if (dv < best) { best = dv; bi = red_i[qt * 64 + row]; }
                }
                float* qp = qb + row * STRIDE + s * 16;
                const float* hp = rb + bi * 16;
                float lsum = 0.f;
                #pragma unroll
                for (int d = 0; d < 16; ++d) {
                    const float qvv = qp[d];
                    const float hv  = hp[d];
                    const float e   = qvv - hv;
                    lsum = fmaf(e, e, lsum);
                    qp[d] = hv;   // quant = hard (forward value)
                }
                loss_acc += lsum;
            }
        }
        __syncthreads();

        mm64<1>(rb, qb, wtD, b_dq + L * 64, deqf, lane, w); // deq -> rb, C-frags kept
        __syncthreads();
        mm64<2>(nullptr, rb, wtR, b_rh + L * 64, restored, lane, w);  // restored += deq@Wrh + b
        if (L < 2)
            mm64<3>(qb, zb, wtL, b_lh + L * 64, deqf, lane, w);       // resid = z@Wlh + b - deq -> qb
        __syncthreads();
        float* tmp = rb; rb = qb; qb = tmp;
    }

    // loss: wave shuffle-reduce -> LDS -> one atomic per block
    #pragma unroll
    for (int off = 32; off > 0; off >>= 1) loss_acc += __shfl_down(loss_acc, off, 64);
    if (lane == 0) wred[w] = loss_acc;

    // restored C-frags -> zb (dead) -> coalesced global store
    {
        const int rg = g2 * 4;
        #pragma unroll
        for (int ct = 0; ct < 4; ++ct)
            #pragma unroll
            for (int j = 0; j < 4; ++j)
                zb[(w * 16 + rg + j) * STRIDE + ct * 16 + lc] = restored[ct][j];
    }
    __syncthreads();
    for (int i = 0; i < 16; ++i) {
        const int e = t + 256 * i;
        const int c = e >> 6, r = e & 63;
        out[base + (size_t)c * HW + r] = zb[r * STRIDE + c];
    }
    if (t == 0) {
        const float tot = (wred[0] + wred[1]) + (wred[2] + wred[3]);
        atomicAdd(loss_out, tot * (1.25f / 16777216.0f));
    }
}

extern "C" void kernel_launch(void* const* d_in, const int* in_sizes, int n_in,
                              void* d_out, int out_size, void* d_ws, size_t ws_size,
                              hipStream_t stream) {
    const float* x     = (const float*)d_in[0];
    const float* W_enc = (const float*)d_in[1];
    const float* b_enc = (const float*)d_in[2];
    const float* W_qh  = (const float*)d_in[3];
    const float* b_qh  = (const float*)d_in[4];
    const float* W_lh  = (const float*)d_in[5];
    const float* b_lh  = (const float*)d_in[6];
    const float* W_dq  = (const float*)d_in[7];
    const float* b_dq  = (const float*)d_in[8];
    const float* W_rh  = (const float*)d_in[9];
    const float* b_rh  = (const float*)d_in[10];
    const float* cbk   = (const float*)d_in[11];

    float* out      = (float*)d_out;
    float* loss_out = out + (out_size - 1);

    __bf16* ws = (__bf16*)d_ws;   // 15*12288 bf16 = 360 KB

    hipMemsetAsync(loss_out, 0, sizeof(float), stream);
    hpp_prep<<<dim3(240), dim3(256), 0, stream>>>(W_enc, W_qh, W_dq, W_rh, W_lh, ws);
    hpp_fused<<<dim3(4096), dim3(256), 0, stream>>>(
        x, b_enc, b_qh, b_lh, b_dq, b_rh, cbk, ws, out, loss_out);
}

// Round 4
// 1068.564 us; speedup vs baseline: 1.3993x; 1.1935x over previous
//
#include <hip/hip_runtime.h>

#define HW 65536
#define STRIDE 68   // padded LDS row stride in floats (16B-aligned, breaks bank degeneracy)

typedef float          f32x4  __attribute__((ext_vector_type(4)));
typedef __bf16         bf16x8 __attribute__((ext_vector_type(8)));
typedef unsigned short u16x8  __attribute__((ext_vector_type(8)));

// intra-wave LDS RAW fence (cross-lane within one wave; no barrier needed).
// Ordered consumers are ds_read/ds_write (memory ops), so the "memory" clobber
// suffices (rule-18 hoisting only affects register-only MFMA consumers).
#define LGKM0() asm volatile("s_waitcnt lgkmcnt(0)" ::: "memory")

// ws (__bf16 element offsets):
//   weights: mat m = type*3 + L (type: 0 enc, 1 qh, 2 dq, 3 rh, 4 lh)
//            base m*12288, split levels at +0/+4096/+8192, layout [col][k] (B-frag transposed)
//   codebook splits: base 184320, levels at +0/+49152/+98304, flat [(L*4+s)*256 + code][d]
//   cc: float region at elem offset 331776: cc[(L*4+s)*256 + code]
#define WS_CB 184320
#define WS_CC 331776

__device__ __forceinline__ f32x4 mfma16(bf16x8 a, bf16x8 b, f32x4 c) {
    return __builtin_amdgcn_mfma_f32_16x16x32_bf16(a, b, c, 0, 0, 0);
}

// -------- 3-level bf16 split via BIT OPS ONLY (compiler cannot fold):
// truncation split 8+8+8 mantissa bits, l1+l2+l3 = x to 2^-24 |x|; subtractions exact.
struct AFrag { bf16x8 a1[2], a2[2], a3[2]; };   // 3 levels x 2 K-tiles

__device__ __forceinline__ void split3_8(const float* f, bf16x8* v1, bf16x8* v2, bf16x8* v3) {
    u16x8 a, b, c;
    #pragma unroll
    for (int i = 0; i < 8; ++i) {
        const float    x  = f[i];
        const unsigned u1 = __float_as_uint(x) & 0xFFFF0000u;
        const float    r1 = x - __uint_as_float(u1);          // exact
        const unsigned u2 = __float_as_uint(r1) & 0xFFFF0000u;
        const float    r2 = r1 - __uint_as_float(u2);         // exact
        const unsigned u3 = __float_as_uint(r2) & 0xFFFF0000u;
        a[i] = (unsigned short)(u1 >> 16);
        b[i] = (unsigned short)(u2 >> 16);
        c[i] = (unsigned short)(u3 >> 16);
    }
    union { u16x8 u; bf16x8 b; } cv;
    cv.u = a; *v1 = cv.b;
    cv.u = b; *v2 = cv.b;
    cv.u = c; *v3 = cv.b;
}

// A-frag for mfma_f32_16x16x32_bf16: row = lane&15, k = (lane>>4)*8 + j
__device__ __forceinline__ AFrag load_afrag(const float* __restrict__ buf, int rbase, int lane) {
    const int r  = rbase + (lane & 15);
    const int k0 = (lane >> 4) * 8;
    const float* p = buf + r * STRIDE + k0;
    float f[16];
    *(float4*)(f + 0)  = *(const float4*)(p + 0);
    *(float4*)(f + 4)  = *(const float4*)(p + 4);
    *(float4*)(f + 8)  = *(const float4*)(p + 32);
    *(float4*)(f + 12) = *(const float4*)(p + 36);
    AFrag A;
    split3_8(f,     &A.a1[0], &A.a2[0], &A.a3[0]);
    split3_8(f + 8, &A.a1[1], &A.a2[1], &A.a3[1]);
    return A;
}

// dst = src @ W + b over a 64x64 tile; wave w reads/writes ONLY rows [16w,16w+16) -> wave-local.
// MODE 0: store dst; 1: store dst + save C-frags; 2: sav[] += result (+bias); 3: store dst - sav[]
template<int MODE>
__device__ __forceinline__ void mm64(float* __restrict__ dst, const float* __restrict__ src,
                                     const __bf16* __restrict__ wt, const float* __restrict__ bias,
                                     f32x4* __restrict__ sav, int lane, int w)
{
    const AFrag A = load_afrag(src, w * 16, lane);
    const int lc = lane & 15;
    const int kg = (lane >> 4) * 8;
    const int rg = (lane >> 4) * 4;
    #pragma unroll
    for (int ct = 0; ct < 4; ++ct) {
        const int col = ct * 16 + lc;
        const __bf16* wp = wt + col * 64 + kg;          // B-frag: col = lane&15, k = (lane>>4)*8+j
        const bf16x8 b10 = *(const bf16x8*)(wp);
        const bf16x8 b11 = *(const bf16x8*)(wp + 32);
        const bf16x8 b20 = *(const bf16x8*)(wp + 4096);
        const bf16x8 b21 = *(const bf16x8*)(wp + 4096 + 32);
        const bf16x8 b30 = *(const bf16x8*)(wp + 8192);
        const bf16x8 b31 = *(const bf16x8*)(wp + 8192 + 32);
        const float bv = bias[col];
        f32x4 acc;
        if (MODE == 2) { acc = sav[ct]; acc.x += bv; acc.y += bv; acc.z += bv; acc.w += bv; }
        else           { acc.x = bv; acc.y = bv; acc.z = bv; acc.w = bv; }
        acc = mfma16(A.a1[0], b10, acc); acc = mfma16(A.a1[1], b11, acc);
        acc = mfma16(A.a2[0], b10, acc); acc = mfma16(A.a2[1], b11, acc);
        acc = mfma16(A.a3[0], b10, acc); acc = mfma16(A.a3[1], b11, acc);
        acc = mfma16(A.a1[0], b20, acc); acc = mfma16(A.a1[1], b21, acc);
        acc = mfma16(A.a2[0], b20, acc); acc = mfma16(A.a2[1], b21, acc);
        acc = mfma16(A.a1[0], b30, acc); acc = mfma16(A.a1[1], b31, acc);
        if (MODE == 2) { sav[ct] = acc; continue; }
        if (MODE == 1) sav[ct] = acc;
        if (MODE == 3) { const f32x4 d = sav[ct]; acc.x -= d.x; acc.y -= d.y; acc.z -= d.z; acc.w -= d.w; }
        // C-frag: col = lane&15, row = (lane>>4)*4 + j   [measured m89]
        #pragma unroll
        for (int j = 0; j < 4; ++j)
            dst[(w * 16 + rg + j) * STRIDE + col] = acc[j];
    }
}

// ---------------- prep: bit-split weights (transposed), codebooks, cc into ws ----------------
__global__ __launch_bounds__(256)
void hpp_prep(const float* __restrict__ W_enc, const float* __restrict__ W_qh,
              const float* __restrict__ W_dq,  const float* __restrict__ W_rh,
              const float* __restrict__ W_lh,  const float* __restrict__ cbk,
              __bf16* __restrict__ ws)
{
    const int i = blockIdx.x * 256 + threadIdx.x;
    if (i < 61440) {                       // 15 mats x 4096
        const int m = i >> 12, e = i & 4095;
        const int t = m / 3, L = m - t * 3;
        const int c = e >> 6, k = e & 63;
        const float* W = (t == 0) ? W_enc : (t == 1) ? W_qh : (t == 2) ? W_dq
                                        : (t == 3) ? W_rh : W_lh;
        const float    fv = W[L * 4096 + k * 64 + c];
        const unsigned u1 = __float_as_uint(fv) & 0xFFFF0000u;
        const float    r1 = fv - __uint_as_float(u1);
        const unsigned u2 = __float_as_uint(r1) & 0xFFFF0000u;
        const float    r2 = r1 - __uint_as_float(u2);
        const unsigned u3 = __float_as_uint(r2) & 0xFFFF0000u;
        unsigned short* wp = (unsigned short*)(ws + m * 12288 + c * 64 + k);  // transposed: [col][k]
        wp[0]    = (unsigned short)(u1 >> 16);
        wp[4096] = (unsigned short)(u2 >> 16);
        wp[8192] = (unsigned short)(u3 >> 16);
    } else if (i < 110592) {               // codebook splits: 3*4*256*16
        const int j = i - 61440;
        const float    fv = cbk[j];
        const unsigned u1 = __float_as_uint(fv) & 0xFFFF0000u;
        const float    r1 = fv - __uint_as_float(u1);
        const unsigned u2 = __float_as_uint(r1) & 0xFFFF0000u;
        const float    r2 = r1 - __uint_as_float(u2);
        const unsigned u3 = __float_as_uint(r2) & 0xFFFF0000u;
        unsigned short* cp = (unsigned short*)(ws + WS_CB + j);
        cp[0]     = (unsigned short)(u1 >> 16);
        cp[49152] = (unsigned short)(u2 >> 16);
        cp[98304] = (unsigned short)(u3 >> 16);
    } else if (i < 113664) {               // cc = ||code||^2: 3*4*256
        const int j = i - 110592;
        const float* cp = cbk + (size_t)j * 16;
        float s0 = 0.f;
        #pragma unroll
        for (int d = 0; d < 16; ++d) s0 = fmaf(cp[d], cp[d], s0);
        ((float*)(ws + WS_CC))[j] = s0;
    }
}

// ---------------- main fused kernel: 64 rows / block ----------------
__global__ __launch_bounds__(256, 2)
void hpp_fused(const float* __restrict__ x,
               const float* __restrict__ b_enc, const float* __restrict__ b_qh,
               const float* __restrict__ b_lh,  const float* __restrict__ b_dq,
               const float* __restrict__ b_rh,
               const float* __restrict__ cbk,   const __bf16* __restrict__ ws,
               float* __restrict__ out, float* __restrict__ loss_out)
{
    __shared__ __align__(16) float buf0[64 * STRIDE];
    __shared__ __align__(16) float buf1[64 * STRIDE];
    __shared__ __align__(16) float buf2[64 * STRIDE];
    __shared__ float red_d[256];
    __shared__ int   red_i[256];
    __shared__ float wred[4];

    const int t   = threadIdx.x;
    const int n0  = blockIdx.x * 64;
    const int b   = n0 >> 16;
    const int hw0 = n0 & (HW - 1);
    const size_t base = (size_t)b * 64 * HW + hw0;

    float* rb = buf0;   // residual (then deq)
    float* zb = buf1;   // z (then restored staging)
    float* qb = buf2;   // q (then quant, then next residual)

    for (int i = 0; i < 16; ++i) {
        const int e = t + 256 * i;
        const int c = e >> 6, r = e & 63;
        rb[r * STRIDE + c] = x[base + (size_t)c * HW + r];
    }

    const int lane = t & 63;
    const int w    = t >> 6;         // wave id: GEMM row-block AND VQ subspace
    const int lc   = lane & 15;
    const int g2   = lane >> 4;

    f32x4 restored[4] = {};
    f32x4 deqf[4];
    float loss_acc = 0.f;

    const float* ccp_all = (const float*)(ws + WS_CC);

    __syncthreads();   // staged x visible to all waves

    for (int L = 0; L < 3; ++L) {
        const __bf16* wtE = ws + (0 * 3 + L) * 12288;
        const __bf16* wtQ = ws + (1 * 3 + L) * 12288;
        const __bf16* wtD = ws + (2 * 3 + L) * 12288;
        const __bf16* wtR = ws + (3 * 3 + L) * 12288;
        const __bf16* wtL = ws + (4 * 3 + L) * 12288;

        mm64<0>(zb, rb, wtE, b_enc + L * 64, nullptr, lane, w);   // z = r@We + b   [wave-local]
        LGKM0();
        mm64<0>(qb, zb, wtQ, b_qh + L * 64, nullptr, lane, w);    // q = z@Wq + b   [wave-local]
        __syncthreads();   // qb visible to all waves (scan reads all rows)

        // ---- VQ scan via packed split-MFMA: wave w = subspace s=w, all 64 rows ----
        // dist - qq = cc - 2*q.c ; products (1,1)(2,2)(1,2)(2,1)(1,3)(3,1) kept -> 2^-24 class.
        {
            const int ls   = L * 4 + w;
            const int dsel = (g2 & 1) * 8;
            const __bf16* cbL = ws + WS_CB + ls * 4096;
            const __bf16* bp1 = cbL + (g2 < 2 ? 0 : 1) * 49152;
            const __bf16* bp2 = cbL + (g2 < 2 ? 1 : 0) * 49152;
            const __bf16* bp3 = cbL + (g2 < 2 ? 2 : 0) * 49152;
            const float*  ccp = ccp_all + ls * 256;

            for (int rt = 0; rt < 4; ++rt) {
                const int row = rt * 16 + lc;
                const float* qp = qb + row * STRIDE + w * 16 + dsel;
                float f[8];
                *(float4*)(f + 0) = *(const float4*)(qp + 0);
                *(float4*)(f + 4) = *(const float4*)(qp + 4);
                bf16x8 q1, q2, q3;
                {   // bit-op split of v = -2*q (fold the -2)
                    u16x8 ua, ub, uc;
                    #pragma unroll
                    for (int i2 = 0; i2 < 8; ++i2) {
                        const float    v  = -2.0f * f[i2];
                        const unsigned u1 = __float_as_uint(v) & 0xFFFF0000u;
                        const float    r1 = v - __uint_as_float(u1);
                        const unsigned u2 = __float_as_uint(r1) & 0xFFFF0000u;
                        const float    r2 = r1 - __uint_as_float(u2);
                        const unsigned u3 = __float_as_uint(r2) & 0xFFFF0000u;
                        ua[i2] = (unsigned short)(u1 >> 16);
                        ub[i2] = (unsigned short)(u2 >> 16);
                        uc[i2] = (unsigned short)(u3 >> 16);
                    }
                    union { u16x8 u; bf16x8 b; } cv;
                    cv.u = ua; q1 = cv.b;
                    cv.u = ub; q2 = cv.b;
                    cv.u = uc; q3 = cv.b;
                }
                const bf16x8 a12 = (g2 < 2) ? q1 : q2;
                const bf16x8 a13 = (g2 < 2) ? q1 : q3;

                float bd[4]; int bi[4];
                #pragma unroll
                for (int j = 0; j < 4; ++j) { bd[j] = 3.4e38f; bi[j] = 0; }

                #pragma unroll 4
                for (int ct = 0; ct < 16; ++ct) {
                    const int code = ct * 16 + lc;
                    const int co   = code * 16 + dsel;
                    const bf16x8 B1 = *(const bf16x8*)(bp1 + co);
                    const bf16x8 B2 = *(const bf16x8*)(bp2 + co);
                    const bf16x8 B3 = *(const bf16x8*)(bp3 + co);
                    const float ccv = ccp[code];
                    f32x4 acc = {ccv, ccv, ccv, ccv};       // fold cc into C-init
                    acc = mfma16(a12, B1, acc);
                    acc = mfma16(a12, B2, acc);
                    acc = mfma16(a13, B3, acc);
                    #pragma unroll
                    for (int j = 0; j < 4; ++j)
                        if (acc[j] < bd[j]) { bd[j] = acc[j]; bi[j] = code; }  // asc => first-min
                }
                #pragma unroll
                for (int j = 0; j < 4; ++j) {               // min across the 16 code-lanes
                    float d = bd[j]; int ix = bi[j];
                    #pragma unroll
                    for (int m = 1; m < 16; m <<= 1) {
                        const float od = __shfl_xor(d, m, 64);
                        const int   oi = __shfl_xor(ix, m, 64);
                        if (od < d || (od == d && oi < ix)) { d = od; ix = oi; }
                    }
                    if (lc == 0) {
                        red_d[w * 64 + rt * 16 + g2 * 4 + j] = d;   // row = rt*16 + g2*4 + j
                        red_i[w * 64 + rt * 16 + g2 * 4 + j] = ix;
                    }
                }
            }
        }
        LGKM0();   // red_* visibility within the wave (cross-wave sections are disjoint)

        // ---- quantize in place + loss: thread = (s = w, row = lane); all 256 active ----
        {
            const int s = w, row = lane;
            const float bdv = red_d[s * 64 + row];          // = cc - 2*q.c
            const int   biv = red_i[s * 64 + row];
            float* qp = qb + row * STRIDE + s * 16;
            float qv[16];
            *(float4*)(qv + 0)  = *(const float4*)(qp + 0);
            *(float4*)(qv + 4)  = *(const float4*)(qp + 4);
            *(float4*)(qv + 8)  = *(const float4*)(qp + 8);
            *(float4*)(qv + 12) = *(const float4*)(qp + 12);
            float qq = 0.f;
            #pragma unroll
            for (int d = 0; d < 16; ++d) qq = fmaf(qv[d], qv[d], qq);
            loss_acc += bdv + qq;                           // ||q-hard||^2 = qq - 2dot + cc
            const float* hp = cbk + ((size_t)(L * 4 + s) * 256 + biv) * 16;
            *(float4*)(qp + 0)  = *(const float4*)(hp + 0);
            *(float4*)(qp + 4)  = *(const float4*)(hp + 4);
            *(float4*)(qp + 8)  = *(const float4*)(hp + 8);
            *(float4*)(qp + 12) = *(const float4*)(hp + 12);
        }
        __syncthreads();   // quantized qb visible to all waves (D reads all cols)

        mm64<1>(rb, qb, wtD, b_dq + L * 64, deqf, lane, w); // deq -> rb   [wave-local]
        LGKM0();
        mm64<2>(nullptr, rb, wtR, b_rh + L * 64, restored, lane, w);  // restored += deq@Wrh + b
        if (L < 2)
            mm64<3>(qb, zb, wtL, b_lh + L * 64, deqf, lane, w);       // resid = z@Wlh + b - deq
        LGKM0();   // qb (next residual) RAW for next-level E in this wave
        float* tmp = rb; rb = qb; qb = tmp;
    }

    // loss: wave shuffle-reduce -> LDS -> one atomic per block
    #pragma unroll
    for (int off = 32; off > 0; off >>= 1) loss_acc += __shfl_down(loss_acc, off, 64);
    if (lane == 0) wred[w] = loss_acc;

    // restored C-frags -> zb (dead) -> coalesced global store
    {
        const int rg = g2 * 4;
        #pragma unroll
        for (int ct = 0; ct < 4; ++ct)
            #pragma unroll
            for (int j = 0; j < 4; ++j)
                zb[(w * 16 + rg + j) * STRIDE + ct * 16 + lc] = restored[ct][j];
    }
    __syncthreads();
    for (int i = 0; i < 16; ++i) {
        const int e = t + 256 * i;
        const int c = e >> 6, r = e & 63;
        out[base + (size_t)c * HW + r] = zb[r * STRIDE + c];
    }
    if (t == 0) {
        const float tot = (wred[0] + wred[1]) + (wred[2] + wred[3]);
        atomicAdd(loss_out, tot * (1.25f / 16777216.0f));
    }
}

extern "C" void kernel_launch(void* const* d_in, const int* in_sizes, int n_in,
                              void* d_out, int out_size, void* d_ws, size_t ws_size,
                              hipStream_t stream) {
    const float* x     = (const float*)d_in[0];
    const float* W_enc = (const float*)d_in[1];
    const float* b_enc = (const float*)d_in[2];
    const float* W_qh  = (const float*)d_in[3];
    const float* b_qh  = (const float*)d_in[4];
    const float* W_lh  = (const float*)d_in[5];
    const float* b_lh  = (const float*)d_in[6];
    const float* W_dq  = (const float*)d_in[7];
    const float* b_dq  = (const float*)d_in[8];
    const float* W_rh  = (const float*)d_in[9];
    const float* b_rh  = (const float*)d_in[10];
    const float* cbk   = (const float*)d_in[11];

    float* out      = (float*)d_out;
    float* loss_out = out + (out_size - 1);

    __bf16* ws = (__bf16*)d_ws;   // ~660 KB: 15*12288 + 3*49152 bf16 + 3072 f32

    hipMemsetAsync(loss_out, 0, sizeof(float), stream);
    hpp_prep<<<dim3(444), dim3(256), 0, stream>>>(W_enc, W_qh, W_dq, W_rh, W_lh, cbk, ws);
    hpp_fused<<<dim3(4096), dim3(256), 0, stream>>>(
        x, b_enc, b_qh, b_lh, b_dq, b_rh, cbk, ws, out, loss_out);
}